// Round 1
// baseline (2554.951 us; speedup 1.0000x reference)
//
#include <hip/hip_runtime.h>
#include <hip/hip_bf16.h>

// GraphVAE forward for MI355X (gfx950).
// Pipeline: deg -> dis -> nrm -> GEMM1(bf16 MFMA, fused bias+nrm) -> scatter ->
//           GEMM2(relu on load) -> scatter -> mean-reduce(relu) -> tail -> bcast.
// Workspace budget: ~390 MB (scaled bf16 128MB + agg f32 256MB + small).

#define FDIM 128

typedef __attribute__((ext_vector_type(8))) short bf16x8;
typedef __attribute__((ext_vector_type(4))) float f32x4;

static __device__ __forceinline__ unsigned short f2bf(float f) {
  union { float f; unsigned u; } v; v.f = f;
  unsigned r = v.u + 0x7FFFu + ((v.u >> 16) & 1u);   // round-to-nearest-even
  return (unsigned short)(r >> 16);
}
static __device__ __forceinline__ float bf2f(unsigned short b) {
  union { unsigned u; float f; } v; v.u = ((unsigned)b) << 16;
  return v.f;
}

// ---------------- degree / norm ----------------
__global__ void count_deg(const int* __restrict__ row, float* __restrict__ deg, int E) {
  int e = blockIdx.x * blockDim.x + threadIdx.x;
  if (e < E) atomicAdd(&deg[row[e]], 1.0f);
}

__global__ void deg2dis(float* __restrict__ deg, int N) {
  int i = blockIdx.x * blockDim.x + threadIdx.x;
  if (i < N) {
    float d = deg[i];
    deg[i] = d > 0.0f ? rsqrtf(d) : 0.0f;
  }
}

__global__ void mknorm(const float* __restrict__ dis, const int* __restrict__ row,
                       const int* __restrict__ col, float* __restrict__ nrm, int N) {
  int i = blockIdx.x * blockDim.x + threadIdx.x;
  if (i < N) nrm[i] = dis[row[i]] * dis[col[i]];
}

// ---------------- GEMM: scaled = (relu?(in) @ W + b) * nrm ----------------
// in: [N,128] f32, W: [128,128] f32 row-major (k,n), out: [N,128] bf16 bits.
// Block = 256 threads (4 waves), tile = 64 rows. W^T and A staged in LDS as
// bf16 with XOR swizzle (byte ^= (row&7)<<4) to kill ds_read_b128 bank conflicts.
template <bool RELU>
__global__ __launch_bounds__(256) void gemm_scale(const float* __restrict__ in,
                                                  const float* __restrict__ W,
                                                  const float* __restrict__ bias,
                                                  const float* __restrict__ nrm,
                                                  unsigned short* __restrict__ out,
                                                  int N) {
  __shared__ unsigned short Wt[128 * 128];  // Wt[n][k], swizzled, 32 KB
  __shared__ unsigned short As[64 * 128];   // As[r][k], swizzled, 16 KB

  const int tid = threadIdx.x;
  const int rowBase = blockIdx.x * 64;

  // Stage W -> Wt[n][k] (bf16, swizzled). Coalesced f32 reads.
#pragma unroll 8
  for (int i = 0; i < 64; ++i) {
    int idx = tid + 256 * i;        // 0..16383
    int k = idx >> 7, n = idx & 127;
    unsigned short b = f2bf(W[idx]);
    int byte = n * 256 + ((k * 2) ^ ((n & 7) << 4));
    Wt[byte >> 1] = b;
  }

  // Stage A tile: 64 rows x 128 cols, float4 loads, bf16 swizzled stores.
  const float4* inf4 = (const float4*)in;
#pragma unroll
  for (int i = 0; i < 8; ++i) {
    int idx = tid + 256 * i;        // 0..2047 float4s
    int r = idx >> 5;               // 32 float4 per row
    int c4 = idx & 31;
    int gr = rowBase + r;
    float4 v = make_float4(0.f, 0.f, 0.f, 0.f);
    if (gr < N) v = inf4[(size_t)gr * 32 + c4];
    if (RELU) {
      v.x = fmaxf(v.x, 0.f); v.y = fmaxf(v.y, 0.f);
      v.z = fmaxf(v.z, 0.f); v.w = fmaxf(v.w, 0.f);
    }
    ushort4 p;
    p.x = f2bf(v.x); p.y = f2bf(v.y); p.z = f2bf(v.z); p.w = f2bf(v.w);
    int byte = r * 256 + ((c4 * 8) ^ ((r & 7) << 4));
    *(ushort4*)((char*)As + byte) = p;
  }
  __syncthreads();

  const int wave = tid >> 6;        // 0..3 -> rows wave*16..+16
  const int lane = tid & 63;
  const int l15 = lane & 15;
  const int lhi = lane >> 4;        // 0..3
  const int wrow = wave * 16;

  f32x4 acc[8] = {};                // 8 col-tiles of 16 cols

#pragma unroll
  for (int kt = 0; kt < 4; ++kt) {
    int arow = wrow + l15;
    int abyte = arow * 256 + ((kt * 64 + lhi * 16) ^ ((arow & 7) << 4));
    bf16x8 afrag = *(const bf16x8*)((char*)As + abyte);
#pragma unroll
    for (int ct = 0; ct < 8; ++ct) {
      int bcol = ct * 16 + l15;
      int bbyte = bcol * 256 + ((kt * 64 + lhi * 16) ^ ((bcol & 7) << 4));
      bf16x8 bfrag = *(const bf16x8*)((char*)Wt + bbyte);
      acc[ct] = __builtin_amdgcn_mfma_f32_16x16x32_bf16(afrag, bfrag, acc[ct], 0, 0, 0);
    }
  }

  // Epilogue: (acc + bias[col]) * nrm[row] -> bf16 out.
  // C/D layout: col = lane&15, row = (lane>>4)*4 + reg  [m89-verified]
  float nv[4];
  int grow0 = rowBase + wrow + lhi * 4;
#pragma unroll
  for (int r = 0; r < 4; ++r) {
    int gr = grow0 + r;
    nv[r] = (gr < N) ? nrm[gr] : 0.f;
  }
#pragma unroll
  for (int ct = 0; ct < 8; ++ct) {
    float bv = bias[ct * 16 + l15];
#pragma unroll
    for (int r = 0; r < 4; ++r) {
      int gr = grow0 + r;
      if (gr < N) {
        float v = (acc[ct][r] + bv) * nv[r];
        out[(size_t)gr * 128 + ct * 16 + l15] = f2bf(v);
      }
    }
  }
}

// ---------------- scatter: agg[row[e]] += scaled[col[e]] ----------------
// 32 lanes per edge; coalesced 256B bf16 gather; 4 f32 atomics per lane.
__global__ __launch_bounds__(256) void scatter_add(const unsigned short* __restrict__ scaled,
                                                   const int* __restrict__ rows,
                                                   const int* __restrict__ cols,
                                                   float* __restrict__ agg, int E) {
  int gt = blockIdx.x * 256 + threadIdx.x;
  int e = gt >> 5;
  int lane = gt & 31;
  if (e >= E) return;
  int r = rows[e];
  int c = cols[e];
  ushort4 v = ((const ushort4*)(scaled + (size_t)c * 128))[lane];
  float* dst = agg + (size_t)r * 128 + lane * 4;
  atomicAdd(dst + 0, bf2f(v.x));
  atomicAdd(dst + 1, bf2f(v.y));
  atomicAdd(dst + 2, bf2f(v.z));
  atomicAdd(dst + 3, bf2f(v.w));
}

// ---------------- mean-reduce with fused relu: g[c] = sum_i relu(agg[i][c]) ----------------
__global__ __launch_bounds__(256) void reduce_mean(const float* __restrict__ agg,
                                                   float* __restrict__ g, int N) {
  __shared__ float sdata[256];
  int tid = threadIdx.x;
  int col = tid & 127;
  int half = tid >> 7;
  int r0 = blockIdx.x * 512;
  int rend = min(r0 + 512, N);
  float s = 0.f;
  for (int r = r0 + half; r < rend; r += 2)
    s += fmaxf(agg[(size_t)r * 128 + col], 0.f);
  sdata[tid] = s;
  __syncthreads();
  if (tid < 128) atomicAdd(&g[tid], sdata[tid] + sdata[tid + 128]);
}

// ---------------- tail: all the tiny ops, single block of 128 ----------------
__global__ void tail_kernel(const float* __restrict__ g, const float* __restrict__ eps,
                            const float* __restrict__ Wmu, const float* __restrict__ bmu,
                            const float* __restrict__ Wlv, const float* __restrict__ blv,
                            const float* __restrict__ Wn, const float* __restrict__ bn,
                            const float* __restrict__ We1, const float* __restrict__ be1,
                            const float* __restrict__ We2, const float* __restrict__ be2,
                            float* __restrict__ out, float* __restrict__ el4,
                            int N, int E) {
  __shared__ float gm[128], zs[32], eh[128];
  int t = threadIdx.x;
  gm[t] = g[t] / (float)N;
  __syncthreads();
  if (t < 32) {
    float mu = bmu[t], lv = blv[t];
#pragma unroll 8
    for (int k = 0; k < 128; ++k) {
      mu = fmaf(gm[k], Wmu[k * 32 + t], mu);
      lv = fmaf(gm[k], Wlv[k * 32 + t], lv);
    }
    zs[t] = mu + eps[t] * expf(0.5f * lv);
    out[16 + 4 * (size_t)E + t] = mu;          // mu
    out[16 + 4 * (size_t)E + 32 + t] = lv;     // logvar
  }
  __syncthreads();
  if (t < 16) {
    float v = bn[t];
#pragma unroll
    for (int j = 0; j < 32; ++j) v = fmaf(zs[j], Wn[j * 16 + t], v);
    out[t] = v;                                 // node_logits
  }
  {
    float v = be1[t];
#pragma unroll 8
    for (int j = 0; j < 32; ++j)
      v = fmaf(zs[j], We1[j * 128 + t] + We1[(j + 32) * 128 + t], v);
    eh[t] = fmaxf(v, 0.f);
  }
  __syncthreads();
  if (t < 4) {
    float v = be2[t];
#pragma unroll 8
    for (int k = 0; k < 128; ++k) v = fmaf(eh[k], We2[k * 4 + t], v);
    el4[t] = v;
  }
}

// ---------------- broadcast edge_logits ----------------
__global__ __launch_bounds__(256) void bcast_edges(const float* __restrict__ el4,
                                                   float* __restrict__ out16, int E) {
  int i = blockIdx.x * 256 + threadIdx.x;
  if (i < E) {
    float4 v = *(const float4*)el4;
    ((float4*)out16)[i] = v;
  }
}

extern "C" void kernel_launch(void* const* d_in, const int* in_sizes, int n_in,
                              void* d_out, int out_size, void* d_ws, size_t ws_size,
                              hipStream_t stream) {
  const float* x   = (const float*)d_in[0];
  const int*   ei  = (const int*)d_in[1];
  const float* eps = (const float*)d_in[2];
  const float* W1  = (const float*)d_in[3];
  const float* b1  = (const float*)d_in[4];
  const float* W2  = (const float*)d_in[5];
  const float* b2  = (const float*)d_in[6];
  const float* Wmu = (const float*)d_in[7];
  const float* bmu = (const float*)d_in[8];
  const float* Wlv = (const float*)d_in[9];
  const float* blv = (const float*)d_in[10];
  const float* Wn  = (const float*)d_in[11];
  const float* bn  = (const float*)d_in[12];
  const float* We1 = (const float*)d_in[13];
  const float* be1 = (const float*)d_in[14];
  const float* We2 = (const float*)d_in[15];
  const float* be2 = (const float*)d_in[16];

  const int N = in_sizes[0] / FDIM;
  const int E = in_sizes[1] / 2;
  const int* row = ei;
  const int* col = ei + E;
  float* out = (float*)d_out;

  char* ws = (char*)d_ws;
  size_t off = 0;
  float* deg = (float*)(ws + off); off += (size_t)N * 4;
  float* nrm = (float*)(ws + off); off += (size_t)N * 4;
  float* g   = (float*)(ws + off); off += 128 * 4;
  float* el4 = (float*)(ws + off); off += 4 * 4;
  off = (off + 1023) & ~(size_t)1023;
  unsigned short* scaled = (unsigned short*)(ws + off); off += (size_t)N * FDIM * 2;
  off = (off + 1023) & ~(size_t)1023;
  float* agg = (float*)(ws + off); off += (size_t)N * FDIM * 4;

  hipMemsetAsync(deg, 0, (size_t)N * 4, stream);
  hipMemsetAsync(g, 0, (128 + 4) * 4, stream);

  count_deg<<<(E + 255) / 256, 256, 0, stream>>>(row, deg, E);
  deg2dis<<<(N + 255) / 256, 256, 0, stream>>>(deg, N);
  mknorm<<<(N + 255) / 256, 256, 0, stream>>>(deg, row, col, nrm, N);

  gemm_scale<false><<<(N + 63) / 64, 256, 0, stream>>>(x, W1, b1, nrm, scaled, N);
  hipMemsetAsync(agg, 0, (size_t)N * FDIM * 4, stream);
  scatter_add<<<((size_t)E * 32 + 255) / 256, 256, 0, stream>>>(scaled, row, col, agg, E);

  gemm_scale<true><<<(N + 63) / 64, 256, 0, stream>>>(agg, W2, b2, nrm, scaled, N);
  hipMemsetAsync(agg, 0, (size_t)N * FDIM * 4, stream);
  scatter_add<<<((size_t)E * 32 + 255) / 256, 256, 0, stream>>>(scaled, row, col, agg, E);

  reduce_mean<<<(N + 511) / 512, 256, 0, stream>>>(agg, g, N);
  tail_kernel<<<1, 128, 0, stream>>>(g, eps, Wmu, bmu, Wlv, blv, Wn, bn,
                                     We1, be1, We2, be2, out, el4, N, E);
  bcast_edges<<<(E + 255) / 256, 256, 0, stream>>>(el4, out + 16, E);
}

// Round 2
// 961.764 us; speedup vs baseline: 2.6565x; 2.6565x over previous
//
#include <hip/hip_runtime.h>
#include <hip/hip_bf16.h>

// GraphVAE forward for MI355X (gfx950) — round 2: CSR pull-aggregation,
// zero heavy atomics. Pipeline:
//   deg(count) -> scan(rowstart) -> csr fill | dis -> nrm
//   GEMM1(f32 in, bf16 MFMA, fused bias+nrm) -> aggregate1(pull, fused relu, bf16 out)
//   GEMM2(bf16 in) -> aggregate2(pull, fused relu+mean into g)
//   tail -> bcast
// ws usage: ~275 MB.

#define FDIM 128

typedef __attribute__((ext_vector_type(8))) short bf16x8;
typedef __attribute__((ext_vector_type(4))) float f32x4;

static __device__ __forceinline__ unsigned short f2bf(float f) {
  union { float f; unsigned u; } v; v.f = f;
  unsigned r = v.u + 0x7FFFu + ((v.u >> 16) & 1u);   // round-to-nearest-even
  return (unsigned short)(r >> 16);
}
static __device__ __forceinline__ float bf2f(unsigned short b) {
  union { unsigned u; float f; } v; v.u = ((unsigned)b) << 16;
  return v.f;
}

// ---------------- degree / norm ----------------
__global__ void count_deg(const int* __restrict__ row, float* __restrict__ deg, int E) {
  int e = blockIdx.x * blockDim.x + threadIdx.x;
  if (e < E) atomicAdd(&deg[row[e]], 1.0f);
}

__global__ void deg2dis(const float* __restrict__ deg, float* __restrict__ dis, int N) {
  int i = blockIdx.x * blockDim.x + threadIdx.x;
  if (i < N) {
    float d = deg[i];
    dis[i] = d > 0.0f ? rsqrtf(d) : 0.0f;
  }
}

__global__ void mknorm(const float* __restrict__ dis, const int* __restrict__ row,
                       const int* __restrict__ col, float* __restrict__ nrm, int E) {
  int i = blockIdx.x * blockDim.x + threadIdx.x;
  if (i < E) nrm[i] = dis[row[i]] * dis[col[i]];
}

// ---------------- block scan for CSR rowstart ----------------
#define SCAN_B 256

// Per-block exclusive scan of (int)deg; rs[i] = local exclusive, part[b] = block sum.
__global__ __launch_bounds__(SCAN_B) void scan1(const float* __restrict__ deg,
                                                int* __restrict__ rs,
                                                int* __restrict__ part, int N) {
  __shared__ int s[SCAN_B];
  int t = threadIdx.x, i = blockIdx.x * SCAN_B + t;
  int v = (i < N) ? (int)deg[i] : 0;
  s[t] = v;
  __syncthreads();
  for (int off = 1; off < SCAN_B; off <<= 1) {
    int x = (t >= off) ? s[t - off] : 0;
    __syncthreads();
    s[t] += x;
    __syncthreads();
  }
  if (i < N) rs[i] = s[t] - v;
  if (t == SCAN_B - 1) part[blockIdx.x] = s[t];
}

// Single-block exclusive scan of part[] (serial over chunks with carry).
__global__ __launch_bounds__(SCAN_B) void scan2(int* __restrict__ part, int nblk) {
  __shared__ int s[SCAN_B];
  int t = threadIdx.x;
  int carry = 0;
  for (int base = 0; base < nblk; base += SCAN_B) {
    int i = base + t;
    int v = (i < nblk) ? part[i] : 0;
    s[t] = v;
    __syncthreads();
    for (int off = 1; off < SCAN_B; off <<= 1) {
      int x = (t >= off) ? s[t - off] : 0;
      __syncthreads();
      s[t] += x;
      __syncthreads();
    }
    if (i < nblk) part[i] = carry + s[t] - v;
    int tot = s[SCAN_B - 1];
    __syncthreads();
    carry += tot;
  }
}

// rs[i] += part[block]; cursor[i] = rs[i]; rs[N] = E.
__global__ __launch_bounds__(SCAN_B) void scan3(int* __restrict__ rs, const int* __restrict__ part,
                                                int* __restrict__ cursor, int N, int E) {
  int t = threadIdx.x, i = blockIdx.x * SCAN_B + t;
  if (i < N) {
    int v = rs[i] + part[blockIdx.x];
    rs[i] = v;
    cursor[i] = v;
  }
  if (i == 0) rs[N] = E;
}

__global__ void fill_csr(const int* __restrict__ row, const int* __restrict__ col,
                         int* __restrict__ cursor, int* __restrict__ csr_col, int E) {
  int e = blockIdx.x * blockDim.x + threadIdx.x;
  if (e < E) {
    int p = atomicAdd(&cursor[row[e]], 1);
    csr_col[p] = col[e];
  }
}

// ---------------- GEMM: scaled = (in @ W + b) * nrm ----------------
// in: [N,128] f32 or bf16; W: [128,128] f32 (k,n); out: [N,128] bf16 bits.
// Block = 256 threads (4 waves), tile = 64 rows. W^T and A staged in LDS as
// bf16 with XOR swizzle (byte ^= (row&7)<<4) for conflict-free ds_read_b128.
template <bool BF16IN>
__global__ __launch_bounds__(256) void gemm_scale(const void* __restrict__ in_,
                                                  const float* __restrict__ W,
                                                  const float* __restrict__ bias,
                                                  const float* __restrict__ nrm,
                                                  unsigned short* __restrict__ out,
                                                  int N) {
  __shared__ unsigned short Wt[128 * 128];  // Wt[n][k], swizzled, 32 KB
  __shared__ unsigned short As[64 * 128];   // As[r][k], swizzled, 16 KB

  const int tid = threadIdx.x;
  const int rowBase = blockIdx.x * 64;

  // Stage W -> Wt[n][k] (bf16, swizzled). Coalesced f32 reads.
#pragma unroll 8
  for (int i = 0; i < 64; ++i) {
    int idx = tid + 256 * i;        // 0..16383
    int k = idx >> 7, n = idx & 127;
    unsigned short b = f2bf(W[idx]);
    int byte = n * 256 + ((k * 2) ^ ((n & 7) << 4));
    Wt[byte >> 1] = b;
  }

  // Stage A tile: 64 rows x 128 cols -> bf16 swizzled.
  if (BF16IN) {
    const unsigned short* in = (const unsigned short*)in_;
#pragma unroll
    for (int i = 0; i < 4; ++i) {
      int idx = tid + 256 * i;      // 0..1023 x 16B
      int r = idx >> 4;             // 16 ushort8 per row
      int c8 = idx & 15;
      int gr = rowBase + r;
      ushort4 lo = make_ushort4(0, 0, 0, 0), hi = make_ushort4(0, 0, 0, 0);
      if (gr < N) {
        const ushort4* src = (const ushort4*)(in + (size_t)gr * 128) + c8 * 2;
        lo = src[0]; hi = src[1];
      }
      int byte = r * 256 + ((c8 * 16) ^ ((r & 7) << 4));
      *(ushort4*)((char*)As + byte) = lo;
      *(ushort4*)((char*)As + byte + 8) = hi;
    }
  } else {
    const float4* inf4 = (const float4*)in_;
#pragma unroll
    for (int i = 0; i < 8; ++i) {
      int idx = tid + 256 * i;      // 0..2047 float4s
      int r = idx >> 5;             // 32 float4 per row
      int c4 = idx & 31;
      int gr = rowBase + r;
      float4 v = make_float4(0.f, 0.f, 0.f, 0.f);
      if (gr < N) v = inf4[(size_t)gr * 32 + c4];
      ushort4 p;
      p.x = f2bf(v.x); p.y = f2bf(v.y); p.z = f2bf(v.z); p.w = f2bf(v.w);
      int byte = r * 256 + ((c4 * 8) ^ ((r & 7) << 4));
      *(ushort4*)((char*)As + byte) = p;
    }
  }
  __syncthreads();

  const int wave = tid >> 6;        // 0..3 -> rows wave*16..+16
  const int lane = tid & 63;
  const int l15 = lane & 15;
  const int lhi = lane >> 4;        // 0..3
  const int wrow = wave * 16;

  f32x4 acc[8] = {};                // 8 col-tiles of 16 cols

#pragma unroll
  for (int kt = 0; kt < 4; ++kt) {
    int arow = wrow + l15;
    int abyte = arow * 256 + ((kt * 64 + lhi * 16) ^ ((arow & 7) << 4));
    bf16x8 afrag = *(const bf16x8*)((char*)As + abyte);
#pragma unroll
    for (int ct = 0; ct < 8; ++ct) {
      int bcol = ct * 16 + l15;
      int bbyte = bcol * 256 + ((kt * 64 + lhi * 16) ^ ((bcol & 7) << 4));
      bf16x8 bfrag = *(const bf16x8*)((char*)Wt + bbyte);
      acc[ct] = __builtin_amdgcn_mfma_f32_16x16x32_bf16(afrag, bfrag, acc[ct], 0, 0, 0);
    }
  }

  // Epilogue: (acc + bias[col]) * nrm[row] -> bf16 out.
  // C/D layout: col = lane&15, row = (lane>>4)*4 + reg  [m89-verified]
  float nv[4];
  int grow0 = rowBase + wrow + lhi * 4;
#pragma unroll
  for (int r = 0; r < 4; ++r) {
    int gr = grow0 + r;
    nv[r] = (gr < N) ? nrm[gr] : 0.f;
  }
#pragma unroll
  for (int ct = 0; ct < 8; ++ct) {
    float bv = bias[ct * 16 + l15];
#pragma unroll
    for (int r = 0; r < 4; ++r) {
      int gr = grow0 + r;
      if (gr < N) {
        float v = (acc[ct][r] + bv) * nv[r];
        out[(size_t)gr * 128 + ct * 16 + l15] = f2bf(v);
      }
    }
  }
}

// ---------------- aggregate1: h1[r] = relu(sum_{e in csr[r]} scaled[col[e]]) (bf16) ----
// 32 lanes per destination node; coalesced 256B gathers; no atomics.
__global__ __launch_bounds__(256) void aggregate_h(const unsigned short* __restrict__ scaled,
                                                   const int* __restrict__ rs,
                                                   const int* __restrict__ csr_col,
                                                   unsigned short* __restrict__ h1, int N) {
  int gt = blockIdx.x * 256 + threadIdx.x;
  int node = gt >> 5, lane = gt & 31;
  if (node >= N) return;
  int s = rs[node], e = rs[node + 1];
  float a0 = 0.f, a1 = 0.f, a2 = 0.f, a3 = 0.f;
  for (int j = s; j < e; ++j) {
    int c = csr_col[j];
    ushort4 v = ((const ushort4*)(scaled + (size_t)c * 128))[lane];
    a0 += bf2f(v.x); a1 += bf2f(v.y); a2 += bf2f(v.z); a3 += bf2f(v.w);
  }
  ushort4 o;
  o.x = f2bf(fmaxf(a0, 0.f)); o.y = f2bf(fmaxf(a1, 0.f));
  o.z = f2bf(fmaxf(a2, 0.f)); o.w = f2bf(fmaxf(a3, 0.f));
  ((ushort4*)(h1 + (size_t)node * 128))[lane] = o;
}

// ---------------- aggregate2: g[c] += sum_r relu(agg2[r][c]) (never materialized) ----
__global__ __launch_bounds__(256) void aggregate_mean(const unsigned short* __restrict__ scaled,
                                                      const int* __restrict__ rs,
                                                      const int* __restrict__ csr_col,
                                                      float* __restrict__ g, int N) {
  __shared__ float sd[256 * 4];
  int tid = threadIdx.x, grp = tid >> 5, lane = tid & 31;
  float g0 = 0.f, g1 = 0.f, g2 = 0.f, g3 = 0.f;
  for (int node = blockIdx.x * 8 + grp; node < N; node += gridDim.x * 8) {
    int s = rs[node], e = rs[node + 1];
    float a0 = 0.f, a1 = 0.f, a2 = 0.f, a3 = 0.f;
    for (int j = s; j < e; ++j) {
      int c = csr_col[j];
      ushort4 v = ((const ushort4*)(scaled + (size_t)c * 128))[lane];
      a0 += bf2f(v.x); a1 += bf2f(v.y); a2 += bf2f(v.z); a3 += bf2f(v.w);
    }
    g0 += fmaxf(a0, 0.f); g1 += fmaxf(a1, 0.f);
    g2 += fmaxf(a2, 0.f); g3 += fmaxf(a3, 0.f);
  }
  sd[tid * 4 + 0] = g0; sd[tid * 4 + 1] = g1;
  sd[tid * 4 + 2] = g2; sd[tid * 4 + 3] = g3;
  __syncthreads();
  if (tid < 32) {
    float s0 = 0.f, s1 = 0.f, s2 = 0.f, s3 = 0.f;
#pragma unroll
    for (int q = 0; q < 8; ++q) {
      int b = (q * 32 + tid) * 4;
      s0 += sd[b]; s1 += sd[b + 1]; s2 += sd[b + 2]; s3 += sd[b + 3];
    }
    atomicAdd(&g[tid * 4 + 0], s0);
    atomicAdd(&g[tid * 4 + 1], s1);
    atomicAdd(&g[tid * 4 + 2], s2);
    atomicAdd(&g[tid * 4 + 3], s3);
  }
}

// ---------------- tail: all the tiny ops, single block of 128 ----------------
__global__ void tail_kernel(const float* __restrict__ g, const float* __restrict__ eps,
                            const float* __restrict__ Wmu, const float* __restrict__ bmu,
                            const float* __restrict__ Wlv, const float* __restrict__ blv,
                            const float* __restrict__ Wn, const float* __restrict__ bn,
                            const float* __restrict__ We1, const float* __restrict__ be1,
                            const float* __restrict__ We2, const float* __restrict__ be2,
                            float* __restrict__ out, float* __restrict__ el4,
                            int N, int E) {
  __shared__ float gm[128], zs[32], eh[128];
  int t = threadIdx.x;
  gm[t] = g[t] / (float)N;
  __syncthreads();
  if (t < 32) {
    float mu = bmu[t], lv = blv[t];
#pragma unroll 8
    for (int k = 0; k < 128; ++k) {
      mu = fmaf(gm[k], Wmu[k * 32 + t], mu);
      lv = fmaf(gm[k], Wlv[k * 32 + t], lv);
    }
    zs[t] = mu + eps[t] * expf(0.5f * lv);
    out[16 + 4 * (size_t)E + t] = mu;          // mu
    out[16 + 4 * (size_t)E + 32 + t] = lv;     // logvar
  }
  __syncthreads();
  if (t < 16) {
    float v = bn[t];
#pragma unroll
    for (int j = 0; j < 32; ++j) v = fmaf(zs[j], Wn[j * 16 + t], v);
    out[t] = v;                                 // node_logits
  }
  {
    float v = be1[t];
#pragma unroll 8
    for (int j = 0; j < 32; ++j)
      v = fmaf(zs[j], We1[j * 128 + t] + We1[(j + 32) * 128 + t], v);
    eh[t] = fmaxf(v, 0.f);
  }
  __syncthreads();
  if (t < 4) {
    float v = be2[t];
#pragma unroll 8
    for (int k = 0; k < 128; ++k) v = fmaf(eh[k], We2[k * 4 + t], v);
    el4[t] = v;
  }
}

// ---------------- broadcast edge_logits ----------------
__global__ __launch_bounds__(256) void bcast_edges(const float* __restrict__ el4,
                                                   float* __restrict__ out16, int E) {
  int i = blockIdx.x * 256 + threadIdx.x;
  if (i < E) {
    float4 v = *(const float4*)el4;
    ((float4*)out16)[i] = v;
  }
}

extern "C" void kernel_launch(void* const* d_in, const int* in_sizes, int n_in,
                              void* d_out, int out_size, void* d_ws, size_t ws_size,
                              hipStream_t stream) {
  const float* x   = (const float*)d_in[0];
  const int*   ei  = (const int*)d_in[1];
  const float* eps = (const float*)d_in[2];
  const float* W1  = (const float*)d_in[3];
  const float* b1  = (const float*)d_in[4];
  const float* W2  = (const float*)d_in[5];
  const float* b2  = (const float*)d_in[6];
  const float* Wmu = (const float*)d_in[7];
  const float* bmu = (const float*)d_in[8];
  const float* Wlv = (const float*)d_in[9];
  const float* blv = (const float*)d_in[10];
  const float* Wn  = (const float*)d_in[11];
  const float* bn  = (const float*)d_in[12];
  const float* We1 = (const float*)d_in[13];
  const float* be1 = (const float*)d_in[14];
  const float* We2 = (const float*)d_in[15];
  const float* be2 = (const float*)d_in[16];

  const int N = in_sizes[0] / FDIM;
  const int E = in_sizes[1] / 2;
  const int* row = ei;
  const int* col = ei + E;
  float* out = (float*)d_out;

  const int nscan = (N + SCAN_B - 1) / SCAN_B;

  char* ws = (char*)d_ws;
  size_t off = 0;
  float* deg    = (float*)(ws + off); off += (size_t)N * 4;
  float* dis    = (float*)(ws + off); off += (size_t)N * 4;
  float* nrm    = (float*)(ws + off); off += (size_t)E * 4;
  int*   rs     = (int*)(ws + off);   off += ((size_t)N + 1) * 4;
  int*   cursor = (int*)(ws + off);   off += (size_t)N * 4;
  int*   part   = (int*)(ws + off);   off += (size_t)nscan * 4;
  int*   csrcol = (int*)(ws + off);   off += (size_t)E * 4;
  float* g      = (float*)(ws + off); off += 128 * 4;
  float* el4    = (float*)(ws + off); off += 4 * 4;
  off = (off + 1023) & ~(size_t)1023;
  unsigned short* scaled = (unsigned short*)(ws + off); off += (size_t)N * FDIM * 2;
  off = (off + 1023) & ~(size_t)1023;
  unsigned short* h1     = (unsigned short*)(ws + off); off += (size_t)N * FDIM * 2;

  hipMemsetAsync(deg, 0, (size_t)N * 4, stream);
  hipMemsetAsync(g, 0, 128 * 4, stream);

  // degree + norm
  count_deg<<<(E + 255) / 256, 256, 0, stream>>>(row, deg, E);
  deg2dis<<<(N + 255) / 256, 256, 0, stream>>>(deg, dis, N);
  mknorm<<<(E + 255) / 256, 256, 0, stream>>>(dis, row, col, nrm, E);

  // CSR build (by destination row)
  scan1<<<nscan, SCAN_B, 0, stream>>>(deg, rs, part, N);
  scan2<<<1, SCAN_B, 0, stream>>>(part, nscan);
  scan3<<<nscan, SCAN_B, 0, stream>>>(rs, part, cursor, N, E);
  fill_csr<<<(E + 255) / 256, 256, 0, stream>>>(row, col, cursor, csrcol, E);

  // conv1
  gemm_scale<false><<<(N + 63) / 64, 256, 0, stream>>>(x, W1, b1, nrm, scaled, N);
  aggregate_h<<<((size_t)N * 32 + 255) / 256, 256, 0, stream>>>(scaled, rs, csrcol, h1, N);

  // conv2 (+ fused mean)
  gemm_scale<true><<<(N + 63) / 64, 256, 0, stream>>>(h1, W2, b2, nrm, scaled, N);
  aggregate_mean<<<1024, 256, 0, stream>>>(scaled, rs, csrcol, g, N);

  // tail + broadcast
  tail_kernel<<<1, 128, 0, stream>>>(g, eps, Wmu, bmu, Wlv, blv, Wn, bn,
                                     We1, be1, We2, be2, out, el4, N, E);
  bcast_edges<<<(E + 255) / 256, 256, 0, stream>>>(el4, out + 16, E);
}

// Round 3
// 740.207 us; speedup vs baseline: 3.4517x; 1.2993x over previous
//
#include <hip/hip_runtime.h>
#include <hip/hip_bf16.h>

// GraphVAE forward for MI355X (gfx950) — round 3.
//   prep_w(pre-swizzled bf16 W image) | deg -> scan(+dis) -> csr | nrm
//   GEMM (W resident in LDS via global_load_lds; A global->reg; swapped-operand
//         MFMA so epilogue stores are packed ushort4) -> aggregate (16-lane pull)
//   -> tail -> bcast
// ws usage: ~268 MB.

#define FDIM 128

typedef __attribute__((ext_vector_type(8))) short bf16x8;
typedef __attribute__((ext_vector_type(8))) unsigned short ushort8;
typedef __attribute__((ext_vector_type(4))) float f32x4;

static __device__ __forceinline__ unsigned short f2bf(float f) {
  union { float f; unsigned u; } v; v.f = f;
  unsigned r = v.u + 0x7FFFu + ((v.u >> 16) & 1u);   // round-to-nearest-even
  return (unsigned short)(r >> 16);
}
static __device__ __forceinline__ float bf2f(unsigned short b) {
  union { unsigned u; float f; } v; v.u = ((unsigned)b) << 16;
  return v.f;
}

// ---------------- W pre-swizzle: f32 [k][n] -> bf16 LDS image, XOR-swizzled ----
__global__ void prep_w(const float* __restrict__ W, unsigned short* __restrict__ img) {
  int idx = blockIdx.x * 256 + threadIdx.x;     // 0..16383
  int n = idx & 127, k = idx >> 7;
  unsigned short b = f2bf(W[(size_t)k * 128 + n]);
  int byte = n * 256 + ((k * 2) ^ ((n & 7) << 4));
  img[byte >> 1] = b;
}

// ---------------- degree / norm ----------------
__global__ void count_deg(const int* __restrict__ row, float* __restrict__ deg, int E) {
  int e = blockIdx.x * blockDim.x + threadIdx.x;
  if (e < E) atomicAdd(&deg[row[e]], 1.0f);
}

__global__ void mknorm(const float* __restrict__ dis, const int* __restrict__ row,
                       const int* __restrict__ col, float* __restrict__ nrm, int E) {
  int i = blockIdx.x * blockDim.x + threadIdx.x;
  if (i < E) nrm[i] = dis[row[i]] * dis[col[i]];
}

// ---------------- block scan for CSR rowstart (scan1 also emits dis) ----------
#define SCAN_B 256

__global__ __launch_bounds__(SCAN_B) void scan1(const float* __restrict__ deg,
                                                float* __restrict__ dis,
                                                int* __restrict__ rs,
                                                int* __restrict__ part, int N) {
  __shared__ int s[SCAN_B];
  int t = threadIdx.x, i = blockIdx.x * SCAN_B + t;
  float d = (i < N) ? deg[i] : 0.f;
  if (i < N) dis[i] = d > 0.f ? rsqrtf(d) : 0.f;
  int v = (int)d;
  s[t] = v;
  __syncthreads();
  for (int off = 1; off < SCAN_B; off <<= 1) {
    int x = (t >= off) ? s[t - off] : 0;
    __syncthreads();
    s[t] += x;
    __syncthreads();
  }
  if (i < N) rs[i] = s[t] - v;
  if (t == SCAN_B - 1) part[blockIdx.x] = s[t];
}

__global__ __launch_bounds__(SCAN_B) void scan2(int* __restrict__ part, int nblk) {
  __shared__ int s[SCAN_B];
  int t = threadIdx.x;
  int carry = 0;
  for (int base = 0; base < nblk; base += SCAN_B) {
    int i = base + t;
    int v = (i < nblk) ? part[i] : 0;
    s[t] = v;
    __syncthreads();
    for (int off = 1; off < SCAN_B; off <<= 1) {
      int x = (t >= off) ? s[t - off] : 0;
      __syncthreads();
      s[t] += x;
      __syncthreads();
    }
    if (i < nblk) part[i] = carry + s[t] - v;
    int tot = s[SCAN_B - 1];
    __syncthreads();
    carry += tot;
  }
}

__global__ __launch_bounds__(SCAN_B) void scan3(int* __restrict__ rs, const int* __restrict__ part,
                                                int* __restrict__ cursor, int N, int E) {
  int t = threadIdx.x, i = blockIdx.x * SCAN_B + t;
  if (i < N) {
    int v = rs[i] + part[blockIdx.x];
    rs[i] = v;
    cursor[i] = v;
  }
  if (i == 0) rs[N] = E;
}

__global__ void fill_csr(const int* __restrict__ row, const int* __restrict__ col,
                         int* __restrict__ cursor, int* __restrict__ csr_col, int E) {
  int e = blockIdx.x * blockDim.x + threadIdx.x;
  if (e < E) {
    int p = atomicAdd(&cursor[row[e]], 1);
    csr_col[p] = col[e];
  }
}

// ---------------- GEMM: scaled = (in @ W + b) * nrm ----------------
// W resident in LDS (pre-swizzled image, staged once via global_load_lds).
// A fragments read directly global->reg. Swapped-operand MFMA: D[n][m] so
// lane&15 = output ROW, regs = 4 consecutive output cols -> packed stores.
template <bool BF16IN>
__global__ __launch_bounds__(256) void gemm_scale(const void* __restrict__ in_,
                                                  const unsigned short* __restrict__ Wimg,
                                                  const float* __restrict__ bias,
                                                  const float* __restrict__ nrm,
                                                  unsigned short* __restrict__ out,
                                                  int N, int ntiles) {
  __shared__ unsigned short Wt[128 * 128 / 2 * 1];  // placeholder sizing below
  // NOTE: actual size needed is 128*128 ushort = 32 KB:
  // (declared oddly above to keep one array; fix with real decl)
  // -- real declaration:
  // (we re-declare properly)
  (void)Wt;
  __shared__ unsigned short Wlds[128 * 128];        // 32 KB, swizzled image

  const int tid = threadIdx.x;
  const int wave = tid >> 6, lane = tid & 63;
  const int l15 = lane & 15, lhi = lane >> 4;

  // Stage W image -> LDS, linear copy, 16B per lane per call.
  {
    const char* gsrc = (const char*)Wimg;
    char* ldst = (char*)Wlds;
#pragma unroll
    for (int j = 0; j < 8; ++j) {
      int off = (wave * 8 + j) * 1024;
      __builtin_amdgcn_global_load_lds(
          (const __attribute__((address_space(1))) unsigned int*)(gsrc + off + lane * 16),
          (__attribute__((address_space(3))) unsigned int*)(ldst + off),
          16, 0, 0);
    }
  }
  __syncthreads();

  const int swz = (l15 & 7) << 4;  // bcol&7 == l15&7 for all ct

  for (int tile = blockIdx.x; tile < ntiles; tile += gridDim.x) {
    const int row = tile * 64 + wave * 16 + l15;
    const bool valid = row < N;

    bf16x8 afrag[4];
    if (BF16IN) {
      const unsigned short* in = (const unsigned short*)in_ + (size_t)row * 128 + lhi * 8;
#pragma unroll
      for (int kt = 0; kt < 4; ++kt) {
        bf16x8 f = {};
        if (valid) f = *(const bf16x8*)(in + kt * 32);
        afrag[kt] = f;
      }
    } else {
      const float* in = (const float*)in_ + (size_t)row * 128 + lhi * 8;
#pragma unroll
      for (int kt = 0; kt < 4; ++kt) {
        float4 lo = make_float4(0.f, 0.f, 0.f, 0.f), hi = lo;
        if (valid) {
          lo = *(const float4*)(in + kt * 32);
          hi = *(const float4*)(in + kt * 32 + 4);
        }
        bf16x8 f;
        f[0] = (short)f2bf(lo.x); f[1] = (short)f2bf(lo.y);
        f[2] = (short)f2bf(lo.z); f[3] = (short)f2bf(lo.w);
        f[4] = (short)f2bf(hi.x); f[5] = (short)f2bf(hi.y);
        f[6] = (short)f2bf(hi.z); f[7] = (short)f2bf(hi.w);
        afrag[kt] = f;
      }
    }

    f32x4 acc[8] = {};
#pragma unroll
    for (int kt = 0; kt < 4; ++kt) {
      const int kswz = (kt * 64 + lhi * 16) ^ swz;
#pragma unroll
      for (int ct = 0; ct < 8; ++ct) {
        const int bbyte = (ct * 16 + l15) * 256 + kswz;
        bf16x8 bfrag = *(const bf16x8*)((const char*)Wlds + bbyte);
        // swapped operands: D[n][m]; lane&15 = m (data row), lhi*4+reg = n (col)
        acc[ct] = __builtin_amdgcn_mfma_f32_16x16x32_bf16(bfrag, afrag[kt], acc[ct], 0, 0, 0);
      }
    }

    const float nv = valid ? nrm[row] : 0.f;
    unsigned short* orow = out + (size_t)row * 128 + lhi * 4;
#pragma unroll
    for (int ct = 0; ct < 8; ++ct) {
      float4 bv = *(const float4*)(bias + ct * 16 + lhi * 4);
      if (valid) {
        ushort4 o;
        o.x = f2bf((acc[ct][0] + bv.x) * nv);
        o.y = f2bf((acc[ct][1] + bv.y) * nv);
        o.z = f2bf((acc[ct][2] + bv.z) * nv);
        o.w = f2bf((acc[ct][3] + bv.w) * nv);
        *(ushort4*)(orow + ct * 16) = o;
      }
    }
  }
}

// ---------------- aggregate1: h1[r] = relu(sum_{e in csr[r]} scaled[col[e]]) ----
// 16 lanes per node, 16B vector gathers, no atomics.
__global__ __launch_bounds__(256) void aggregate_h(const unsigned short* __restrict__ scaled,
                                                   const int* __restrict__ rs,
                                                   const int* __restrict__ csr_col,
                                                   unsigned short* __restrict__ h1, int N) {
  int gt = blockIdx.x * 256 + threadIdx.x;
  int node = gt >> 4, lane = gt & 15;
  if (node >= N) return;
  int s = rs[node], e = rs[node + 1];
  float a[8] = {};
  for (int j = s; j < e; ++j) {
    int c = csr_col[j];
    ushort8 v = ((const ushort8*)(scaled + (size_t)c * 128))[lane];
#pragma unroll
    for (int i = 0; i < 8; ++i) a[i] += bf2f(v[i]);
  }
  ushort8 o;
#pragma unroll
  for (int i = 0; i < 8; ++i) o[i] = f2bf(fmaxf(a[i], 0.f));
  ((ushort8*)(h1 + (size_t)node * 128))[lane] = o;
}

// ---------------- aggregate2: g[c] += sum_r relu(agg2[r][c]) (not materialized) ----
__global__ __launch_bounds__(256) void aggregate_mean(const unsigned short* __restrict__ scaled,
                                                      const int* __restrict__ rs,
                                                      const int* __restrict__ csr_col,
                                                      float* __restrict__ g, int N) {
  __shared__ float sd[16][16][8];  // [grp][lane][ch] = 8 KB
  int tid = threadIdx.x, grp = tid >> 4, lane = tid & 15;
  float g8[8] = {};
  for (int node = blockIdx.x * 16 + grp; node < N; node += gridDim.x * 16) {
    int s = rs[node], e = rs[node + 1];
    float a[8] = {};
    for (int j = s; j < e; ++j) {
      int c = csr_col[j];
      ushort8 v = ((const ushort8*)(scaled + (size_t)c * 128))[lane];
#pragma unroll
      for (int i = 0; i < 8; ++i) a[i] += bf2f(v[i]);
    }
#pragma unroll
    for (int i = 0; i < 8; ++i) g8[i] += fmaxf(a[i], 0.f);
  }
#pragma unroll
  for (int i = 0; i < 8; ++i) sd[grp][lane][i] = g8[i];
  __syncthreads();
  if (tid < 128) {
    int l = tid >> 3, j = tid & 7;
    float s = 0.f;
#pragma unroll
    for (int q = 0; q < 16; ++q) s += sd[q][l][j];
    atomicAdd(&g[l * 8 + j], s);
  }
}

// ---------------- tail: all the tiny ops, single block of 128 ----------------
__global__ void tail_kernel(const float* __restrict__ g, const float* __restrict__ eps,
                            const float* __restrict__ Wmu, const float* __restrict__ bmu,
                            const float* __restrict__ Wlv, const float* __restrict__ blv,
                            const float* __restrict__ Wn, const float* __restrict__ bn,
                            const float* __restrict__ We1, const float* __restrict__ be1,
                            const float* __restrict__ We2, const float* __restrict__ be2,
                            float* __restrict__ out, float* __restrict__ el4,
                            int N, int E) {
  __shared__ float gm[128], zs[32], eh[128];
  int t = threadIdx.x;
  gm[t] = g[t] / (float)N;
  __syncthreads();
  if (t < 32) {
    float mu = bmu[t], lv = blv[t];
#pragma unroll 8
    for (int k = 0; k < 128; ++k) {
      mu = fmaf(gm[k], Wmu[k * 32 + t], mu);
      lv = fmaf(gm[k], Wlv[k * 32 + t], lv);
    }
    zs[t] = mu + eps[t] * expf(0.5f * lv);
    out[16 + 4 * (size_t)E + t] = mu;          // mu
    out[16 + 4 * (size_t)E + 32 + t] = lv;     // logvar
  }
  __syncthreads();
  if (t < 16) {
    float v = bn[t];
#pragma unroll
    for (int j = 0; j < 32; ++j) v = fmaf(zs[j], Wn[j * 16 + t], v);
    out[t] = v;                                 // node_logits
  }
  {
    float v = be1[t];
#pragma unroll 8
    for (int j = 0; j < 32; ++j)
      v = fmaf(zs[j], We1[j * 128 + t] + We1[(j + 32) * 128 + t], v);
    eh[t] = fmaxf(v, 0.f);
  }
  __syncthreads();
  if (t < 4) {
    float v = be2[t];
#pragma unroll 8
    for (int k = 0; k < 128; ++k) v = fmaf(eh[k], We2[k * 4 + t], v);
    el4[t] = v;
  }
}

// ---------------- broadcast edge_logits ----------------
__global__ __launch_bounds__(256) void bcast_edges(const float* __restrict__ el4,
                                                   float* __restrict__ out16, int E) {
  int i = blockIdx.x * 256 + threadIdx.x;
  if (i < E) {
    float4 v = *(const float4*)el4;
    ((float4*)out16)[i] = v;
  }
}

extern "C" void kernel_launch(void* const* d_in, const int* in_sizes, int n_in,
                              void* d_out, int out_size, void* d_ws, size_t ws_size,
                              hipStream_t stream) {
  const float* x   = (const float*)d_in[0];
  const int*   ei  = (const int*)d_in[1];
  const float* eps = (const float*)d_in[2];
  const float* W1  = (const float*)d_in[3];
  const float* b1  = (const float*)d_in[4];
  const float* W2  = (const float*)d_in[5];
  const float* b2  = (const float*)d_in[6];
  const float* Wmu = (const float*)d_in[7];
  const float* bmu = (const float*)d_in[8];
  const float* Wlv = (const float*)d_in[9];
  const float* blv = (const float*)d_in[10];
  const float* Wn  = (const float*)d_in[11];
  const float* bn  = (const float*)d_in[12];
  const float* We1 = (const float*)d_in[13];
  const float* be1 = (const float*)d_in[14];
  const float* We2 = (const float*)d_in[15];
  const float* be2 = (const float*)d_in[16];

  const int N = in_sizes[0] / FDIM;
  const int E = in_sizes[1] / 2;
  const int* row = ei;
  const int* col = ei + E;
  float* out = (float*)d_out;

  const int nscan = (N + SCAN_B - 1) / SCAN_B;
  const int ntiles = (N + 63) / 64;

  char* ws = (char*)d_ws;
  size_t off = 0;
  float* deg    = (float*)(ws + off); off += (size_t)N * 4;
  float* dis    = (float*)(ws + off); off += (size_t)N * 4;
  float* nrm    = (float*)(ws + off); off += (size_t)E * 4;
  int*   rs     = (int*)(ws + off);   off += ((size_t)N + 1) * 4;
  int*   cursor = (int*)(ws + off);   off += (size_t)N * 4;
  int*   part   = (int*)(ws + off);   off += (size_t)nscan * 4;
  int*   csrcol = (int*)(ws + off);   off += (size_t)E * 4;
  float* g      = (float*)(ws + off); off += 128 * 4;
  float* el4    = (float*)(ws + off); off += 4 * 4;
  off = (off + 1023) & ~(size_t)1023;
  unsigned short* Wimg1 = (unsigned short*)(ws + off); off += 16384 * 2;
  unsigned short* Wimg2 = (unsigned short*)(ws + off); off += 16384 * 2;
  off = (off + 1023) & ~(size_t)1023;
  unsigned short* scaled = (unsigned short*)(ws + off); off += (size_t)N * FDIM * 2;
  off = (off + 1023) & ~(size_t)1023;
  unsigned short* h1     = (unsigned short*)(ws + off); off += (size_t)N * FDIM * 2;

  hipMemsetAsync(deg, 0, (size_t)N * 4, stream);
  hipMemsetAsync(g, 0, 128 * 4, stream);

  // W images + degree + norm + CSR
  prep_w<<<64, 256, 0, stream>>>(W1, Wimg1);
  prep_w<<<64, 256, 0, stream>>>(W2, Wimg2);
  count_deg<<<(E + 255) / 256, 256, 0, stream>>>(row, deg, E);
  scan1<<<nscan, SCAN_B, 0, stream>>>(deg, dis, rs, part, N);
  scan2<<<1, SCAN_B, 0, stream>>>(part, nscan);
  scan3<<<nscan, SCAN_B, 0, stream>>>(rs, part, cursor, N, E);
  mknorm<<<(E + 255) / 256, 256, 0, stream>>>(dis, row, col, nrm, E);
  fill_csr<<<(E + 255) / 256, 256, 0, stream>>>(row, col, cursor, csrcol, E);

  // conv1
  gemm_scale<false><<<1280, 256, 0, stream>>>(x, Wimg1, b1, nrm, scaled, N, ntiles);
  aggregate_h<<<((size_t)N * 16 + 255) / 256, 256, 0, stream>>>(scaled, rs, csrcol, h1, N);

  // conv2 (+ fused mean)
  gemm_scale<true><<<1280, 256, 0, stream>>>(h1, Wimg2, b2, nrm, scaled, N, ntiles);
  aggregate_mean<<<1024, 256, 0, stream>>>(scaled, rs, csrcol, g, N);

  // tail + broadcast
  tail_kernel<<<1, 128, 0, stream>>>(g, eps, Wmu, bmu, Wlv, blv, Wn, bn,
                                     We1, be1, We2, be2, out, el4, N, E);
  bcast_edges<<<(E + 255) / 256, 256, 0, stream>>>(el4, out + 16, E);
}

// Round 4
// 720.087 us; speedup vs baseline: 3.5481x; 1.0279x over previous
//
#include <hip/hip_runtime.h>
#include <hip/hip_bf16.h>

// GraphVAE forward for MI355X (gfx950) — round 4.
//   prep_w(both W images) | deg -> scan(+dis) -> csr(+norm fused)
//   GEMM1 (W in LDS, A f32 global->reg, swapped-operand MFMA)
//   aggregate_h (4-node batched pull, writes h1 PRE-SWIZZLED for gemm2)
//   GEMM2 (W in LDS; A staged via global_load_lds double-buffer, conflict-free)
//   aggregate_mean (4-node batched pull, fused relu+mean)
//   tail -> bcast
// ws usage: ~268 MB.

#define FDIM 128

typedef __attribute__((ext_vector_type(8))) short bf16x8;
typedef __attribute__((ext_vector_type(8))) unsigned short ushort8;
typedef __attribute__((ext_vector_type(4))) float f32x4;

static __device__ __forceinline__ unsigned short f2bf(float f) {
  union { float f; unsigned u; } v; v.f = f;
  unsigned r = v.u + 0x7FFFu + ((v.u >> 16) & 1u);   // round-to-nearest-even
  return (unsigned short)(r >> 16);
}
static __device__ __forceinline__ float bf2f(unsigned short b) {
  union { unsigned u; float f; } v; v.u = ((unsigned)b) << 16;
  return v.f;
}

// ---------------- W pre-swizzle: f32 [k][n] -> bf16 images (both mats) -------
__global__ void prep_w(const float* __restrict__ W1, const float* __restrict__ W2,
                       unsigned short* __restrict__ img1, unsigned short* __restrict__ img2) {
  int idx = blockIdx.x * 256 + threadIdx.x;     // 0..16383
  int n = idx & 127, k = idx >> 7;
  int byte = n * 256 + ((k * 2) ^ ((n & 7) << 4));
  img1[byte >> 1] = f2bf(W1[(size_t)k * 128 + n]);
  img2[byte >> 1] = f2bf(W2[(size_t)k * 128 + n]);
}

// ---------------- degree ----------------
__global__ void count_deg(const int* __restrict__ row, float* __restrict__ deg, int E) {
  int e = blockIdx.x * blockDim.x + threadIdx.x;
  if (e < E) atomicAdd(&deg[row[e]], 1.0f);
}

// ---------------- block scan for CSR rowstart (also emits dis) ---------------
#define SCAN_B 256

__global__ __launch_bounds__(SCAN_B) void scan1(const float* __restrict__ deg,
                                                float* __restrict__ dis,
                                                int* __restrict__ rs,
                                                int* __restrict__ part, int N) {
  __shared__ int s[SCAN_B];
  int t = threadIdx.x, i = blockIdx.x * SCAN_B + t;
  float d = (i < N) ? deg[i] : 0.f;
  if (i < N) dis[i] = d > 0.f ? rsqrtf(d) : 0.f;
  int v = (int)d;
  s[t] = v;
  __syncthreads();
  for (int off = 1; off < SCAN_B; off <<= 1) {
    int x = (t >= off) ? s[t - off] : 0;
    __syncthreads();
    s[t] += x;
    __syncthreads();
  }
  if (i < N) rs[i] = s[t] - v;
  if (t == SCAN_B - 1) part[blockIdx.x] = s[t];
}

__global__ __launch_bounds__(SCAN_B) void scan2(int* __restrict__ part, int nblk) {
  __shared__ int s[SCAN_B];
  int t = threadIdx.x;
  int carry = 0;
  for (int base = 0; base < nblk; base += SCAN_B) {
    int i = base + t;
    int v = (i < nblk) ? part[i] : 0;
    s[t] = v;
    __syncthreads();
    for (int off = 1; off < SCAN_B; off <<= 1) {
      int x = (t >= off) ? s[t - off] : 0;
      __syncthreads();
      s[t] += x;
      __syncthreads();
    }
    if (i < nblk) part[i] = carry + s[t] - v;
    int tot = s[SCAN_B - 1];
    __syncthreads();
    carry += tot;
  }
}

__global__ __launch_bounds__(SCAN_B) void scan3(int* __restrict__ rs, const int* __restrict__ part,
                                                int* __restrict__ cursor, int N, int E) {
  int t = threadIdx.x, i = blockIdx.x * SCAN_B + t;
  if (i < N) {
    int v = rs[i] + part[blockIdx.x];
    rs[i] = v;
    cursor[i] = v;
  }
  if (i == 0) rs[N] = E;
}

// ---------------- fused CSR fill + edge norm ----------------
__global__ void fill_csr_norm(const int* __restrict__ row, const int* __restrict__ col,
                              const float* __restrict__ dis, int* __restrict__ cursor,
                              int* __restrict__ csr_col, float* __restrict__ nrm, int E) {
  int e = blockIdx.x * blockDim.x + threadIdx.x;
  if (e < E) {
    int r = row[e], c = col[e];
    nrm[e] = dis[r] * dis[c];
    int p = atomicAdd(&cursor[r], 1);
    csr_col[p] = c;
  }
}

// ---------------- GEMM1: scaled = (x @ W + b) * nrm  (f32 in, reg A-path) ----
__global__ __launch_bounds__(256) void gemm1_scale(const float* __restrict__ in,
                                                   const unsigned short* __restrict__ Wimg,
                                                   const float* __restrict__ bias,
                                                   const float* __restrict__ nrm,
                                                   unsigned short* __restrict__ out,
                                                   int N, int ntiles) {
  __shared__ unsigned short Wlds[128 * 128];        // 32 KB, swizzled image

  const int tid = threadIdx.x;
  const int wave = tid >> 6, lane = tid & 63;
  const int l15 = lane & 15, lhi = lane >> 4;

  {
    const char* gsrc = (const char*)Wimg;
    char* ldst = (char*)Wlds;
#pragma unroll
    for (int j = 0; j < 8; ++j) {
      int off = (wave * 8 + j) * 1024;
      __builtin_amdgcn_global_load_lds(
          (const __attribute__((address_space(1))) unsigned int*)(gsrc + off + lane * 16),
          (__attribute__((address_space(3))) unsigned int*)(ldst + off),
          16, 0, 0);
    }
  }
  __syncthreads();

  const int swz = (l15 & 7) << 4;

  for (int tile = blockIdx.x; tile < ntiles; tile += gridDim.x) {
    const int row = tile * 64 + wave * 16 + l15;
    const bool valid = row < N;

    bf16x8 afrag[4];
    {
      const float* inp = in + (size_t)row * 128 + lhi * 8;
#pragma unroll
      for (int kt = 0; kt < 4; ++kt) {
        float4 lo = make_float4(0.f, 0.f, 0.f, 0.f), hi = lo;
        if (valid) {
          lo = *(const float4*)(inp + kt * 32);
          hi = *(const float4*)(inp + kt * 32 + 4);
        }
        bf16x8 f;
        f[0] = (short)f2bf(lo.x); f[1] = (short)f2bf(lo.y);
        f[2] = (short)f2bf(lo.z); f[3] = (short)f2bf(lo.w);
        f[4] = (short)f2bf(hi.x); f[5] = (short)f2bf(hi.y);
        f[6] = (short)f2bf(hi.z); f[7] = (short)f2bf(hi.w);
        afrag[kt] = f;
      }
    }

    f32x4 acc[8] = {};
#pragma unroll
    for (int kt = 0; kt < 4; ++kt) {
      const int kswz = (kt * 64 + lhi * 16) ^ swz;
#pragma unroll
      for (int ct = 0; ct < 8; ++ct) {
        const int bbyte = (ct * 16 + l15) * 256 + kswz;
        bf16x8 bfrag = *(const bf16x8*)((const char*)Wlds + bbyte);
        acc[ct] = __builtin_amdgcn_mfma_f32_16x16x32_bf16(bfrag, afrag[kt], acc[ct], 0, 0, 0);
      }
    }

    const float nv = valid ? nrm[row] : 0.f;
    unsigned short* orow = out + (size_t)row * 128 + lhi * 4;
#pragma unroll
    for (int ct = 0; ct < 8; ++ct) {
      float4 bv = *(const float4*)(bias + ct * 16 + lhi * 4);
      if (valid) {
        ushort4 o;
        o.x = f2bf((acc[ct][0] + bv.x) * nv);
        o.y = f2bf((acc[ct][1] + bv.y) * nv);
        o.z = f2bf((acc[ct][2] + bv.z) * nv);
        o.w = f2bf((acc[ct][3] + bv.w) * nv);
        *(ushort4*)(orow + ct * 16) = o;
      }
    }
  }
}

// ---------------- GEMM2: scaled2 = (h1 @ W + b) * nrm  (bf16 in, LDS A dbuf) --
// h1 is stored PRE-SWIZZLED (chunk ^= row&7), so a linear global_load_lds copy
// yields a conflict-free swizzled LDS image.
__global__ __launch_bounds__(256) void gemm2_scale(const unsigned short* __restrict__ h1,
                                                   const unsigned short* __restrict__ Wimg,
                                                   const float* __restrict__ bias,
                                                   const float* __restrict__ nrm,
                                                   unsigned short* __restrict__ out,
                                                   int N, int ntiles) {
  __shared__ unsigned short Wlds[128 * 128];                  // 32 KB
  __shared__ __align__(16) unsigned short Alds[2][64 * 128];  // 2 x 16 KB

  const int tid = threadIdx.x;
  const int wave = tid >> 6, lane = tid & 63;
  const int l15 = lane & 15, lhi = lane >> 4;

  {
    const char* gsrc = (const char*)Wimg;
    char* ldst = (char*)Wlds;
#pragma unroll
    for (int j = 0; j < 8; ++j) {
      int off = (wave * 8 + j) * 1024;
      __builtin_amdgcn_global_load_lds(
          (const __attribute__((address_space(1))) unsigned int*)(gsrc + off + lane * 16),
          (__attribute__((address_space(3))) unsigned int*)(ldst + off),
          16, 0, 0);
    }
  }

  const int swz = (l15 & 7) << 4;
  const int t0 = blockIdx.x;

  // stage tile t -> Alds[b]: 16 KB linear coalesced copy
  auto stageA = [&](int t, int b) {
    const char* src = (const char*)h1 + (size_t)t * 16384 + tid * 16;
    char* dst = (char*)Alds[b] + tid * 16;
#pragma unroll
    for (int j = 0; j < 4; ++j) {
      __builtin_amdgcn_global_load_lds(
          (const __attribute__((address_space(1))) unsigned int*)(src + j * 4096),
          (__attribute__((address_space(3))) unsigned int*)(dst + j * 4096),
          16, 0, 0);
    }
  };

  if (t0 < ntiles) stageA(t0, 0);
  int cur = 0;

  for (int tile = t0; tile < ntiles; tile += gridDim.x) {
    __syncthreads();                       // drains vmcnt -> Alds[cur] ready
    int tn = tile + gridDim.x;
    if (tn < ntiles) stageA(tn, cur ^ 1);  // overlap next stage with MFMA

    const int arow = wave * 16 + l15;
    const char* Ab = (const char*)Alds[cur];
    bf16x8 afrag[4];
#pragma unroll
    for (int kt = 0; kt < 4; ++kt)
      afrag[kt] = *(const bf16x8*)(Ab + arow * 256 + ((kt * 64 + lhi * 16) ^ ((arow & 7) << 4)));

    f32x4 acc[8] = {};
#pragma unroll
    for (int kt = 0; kt < 4; ++kt) {
      const int kswz = (kt * 64 + lhi * 16) ^ swz;
#pragma unroll
      for (int ct = 0; ct < 8; ++ct) {
        const int bbyte = (ct * 16 + l15) * 256 + kswz;
        bf16x8 bfrag = *(const bf16x8*)((const char*)Wlds + bbyte);
        acc[ct] = __builtin_amdgcn_mfma_f32_16x16x32_bf16(bfrag, afrag[kt], acc[ct], 0, 0, 0);
      }
    }

    const int row = tile * 64 + arow;
    const bool valid = row < N;
    const float nv = valid ? nrm[row] : 0.f;
    unsigned short* orow = out + (size_t)row * 128 + lhi * 4;
#pragma unroll
    for (int ct = 0; ct < 8; ++ct) {
      float4 bv = *(const float4*)(bias + ct * 16 + lhi * 4);
      if (valid) {
        ushort4 o;
        o.x = f2bf((acc[ct][0] + bv.x) * nv);
        o.y = f2bf((acc[ct][1] + bv.y) * nv);
        o.z = f2bf((acc[ct][2] + bv.z) * nv);
        o.w = f2bf((acc[ct][3] + bv.w) * nv);
        *(ushort4*)(orow + ct * 16) = o;
      }
    }
    __syncthreads();                       // all waves done reading Alds[cur]
    cur ^= 1;
  }
}

#define ACC_ADD(A, v) { A[0]+=bf2f(v[0]); A[1]+=bf2f(v[1]); A[2]+=bf2f(v[2]); A[3]+=bf2f(v[3]); \
                        A[4]+=bf2f(v[4]); A[5]+=bf2f(v[5]); A[6]+=bf2f(v[6]); A[7]+=bf2f(v[7]); }

// ---------------- aggregate1: h1[r] = relu(sum scaled[col]) — 4-node batched --
// Writes h1 PRE-SWIZZLED (chunk ^= row&7) for gemm2's linear LDS staging.
__global__ __launch_bounds__(256) void aggregate_h(const unsigned short* __restrict__ scaled,
                                                   const int* __restrict__ rs,
                                                   const int* __restrict__ csr_col,
                                                   unsigned short* __restrict__ h1, int N) {
  int gt = blockIdx.x * 256 + threadIdx.x;
  int grp = gt >> 4, lane = gt & 15;
  int n0 = grp * 4;
  if (n0 >= N) return;
  int e0 = rs[n0];
  int e1 = rs[min(n0 + 1, N)];
  int e2 = rs[min(n0 + 2, N)];
  int e3 = rs[min(n0 + 3, N)];
  int e4 = rs[min(n0 + 4, N)];

  float A0[8] = {}, A1[8] = {}, A2[8] = {}, A3[8] = {};
  for (int j = e0; j < e1; ++j) {
    int c = csr_col[j];
    ushort8 v = ((const ushort8*)(scaled + (size_t)c * 128))[lane];
    ACC_ADD(A0, v)
  }
  for (int j = e1; j < e2; ++j) {
    int c = csr_col[j];
    ushort8 v = ((const ushort8*)(scaled + (size_t)c * 128))[lane];
    ACC_ADD(A1, v)
  }
  for (int j = e2; j < e3; ++j) {
    int c = csr_col[j];
    ushort8 v = ((const ushort8*)(scaled + (size_t)c * 128))[lane];
    ACC_ADD(A2, v)
  }
  for (int j = e3; j < e4; ++j) {
    int c = csr_col[j];
    ushort8 v = ((const ushort8*)(scaled + (size_t)c * 128))[lane];
    ACC_ADD(A3, v)
  }

  ushort8 o;
#pragma unroll
  for (int i = 0; i < 8; ++i) o[i] = f2bf(fmaxf(A0[i], 0.f));
  ((ushort8*)(h1 + (size_t)n0 * 128))[lane ^ (n0 & 7)] = o;
  if (n0 + 1 < N) {
#pragma unroll
    for (int i = 0; i < 8; ++i) o[i] = f2bf(fmaxf(A1[i], 0.f));
    ((ushort8*)(h1 + (size_t)(n0 + 1) * 128))[lane ^ ((n0 + 1) & 7)] = o;
  }
  if (n0 + 2 < N) {
#pragma unroll
    for (int i = 0; i < 8; ++i) o[i] = f2bf(fmaxf(A2[i], 0.f));
    ((ushort8*)(h1 + (size_t)(n0 + 2) * 128))[lane ^ ((n0 + 2) & 7)] = o;
  }
  if (n0 + 3 < N) {
#pragma unroll
    for (int i = 0; i < 8; ++i) o[i] = f2bf(fmaxf(A3[i], 0.f));
    ((ushort8*)(h1 + (size_t)(n0 + 3) * 128))[lane ^ ((n0 + 3) & 7)] = o;
  }
}

// ---------------- aggregate2: g += relu(agg2) summed over nodes — batched -----
__global__ __launch_bounds__(256) void aggregate_mean(const unsigned short* __restrict__ scaled,
                                                      const int* __restrict__ rs,
                                                      const int* __restrict__ csr_col,
                                                      float* __restrict__ g, int N) {
  __shared__ float sd[16][16][8];  // 8 KB
  int tid = threadIdx.x, grp = tid >> 4, lane = tid & 15;
  float acc[8] = {};
  const int step = gridDim.x * 16 * 4;
  for (int n0 = (blockIdx.x * 16 + grp) * 4; n0 < N; n0 += step) {
    int e0 = rs[n0];
    int e1 = rs[min(n0 + 1, N)];
    int e2 = rs[min(n0 + 2, N)];
    int e3 = rs[min(n0 + 3, N)];
    int e4 = rs[min(n0 + 4, N)];
    float A0[8] = {}, A1[8] = {}, A2[8] = {}, A3[8] = {};
    for (int j = e0; j < e1; ++j) {
      int c = csr_col[j];
      ushort8 v = ((const ushort8*)(scaled + (size_t)c * 128))[lane];
      ACC_ADD(A0, v)
    }
    for (int j = e1; j < e2; ++j) {
      int c = csr_col[j];
      ushort8 v = ((const ushort8*)(scaled + (size_t)c * 128))[lane];
      ACC_ADD(A1, v)
    }
    for (int j = e2; j < e3; ++j) {
      int c = csr_col[j];
      ushort8 v = ((const ushort8*)(scaled + (size_t)c * 128))[lane];
      ACC_ADD(A2, v)
    }
    for (int j = e3; j < e4; ++j) {
      int c = csr_col[j];
      ushort8 v = ((const ushort8*)(scaled + (size_t)c * 128))[lane];
      ACC_ADD(A3, v)
    }
#pragma unroll
    for (int i = 0; i < 8; ++i)
      acc[i] += fmaxf(A0[i], 0.f) + fmaxf(A1[i], 0.f) + fmaxf(A2[i], 0.f) + fmaxf(A3[i], 0.f);
  }
#pragma unroll
  for (int i = 0; i < 8; ++i) sd[grp][lane][i] = acc[i];
  __syncthreads();
  if (tid < 128) {
    int l = tid >> 3, j = tid & 7;
    float s = 0.f;
#pragma unroll
    for (int q = 0; q < 16; ++q) s += sd[q][l][j];
    atomicAdd(&g[l * 8 + j], s);
  }
}

// ---------------- tail: all the tiny ops, single block of 128 ----------------
__global__ void tail_kernel(const float* __restrict__ g, const float* __restrict__ eps,
                            const float* __restrict__ Wmu, const float* __restrict__ bmu,
                            const float* __restrict__ Wlv, const float* __restrict__ blv,
                            const float* __restrict__ Wn, const float* __restrict__ bn,
                            const float* __restrict__ We1, const float* __restrict__ be1,
                            const float* __restrict__ We2, const float* __restrict__ be2,
                            float* __restrict__ out, float* __restrict__ el4,
                            int N, int E) {
  __shared__ float gm[128], zs[32], eh[128];
  int t = threadIdx.x;
  gm[t] = g[t] / (float)N;
  __syncthreads();
  if (t < 32) {
    float mu = bmu[t], lv = blv[t];
#pragma unroll 8
    for (int k = 0; k < 128; ++k) {
      mu = fmaf(gm[k], Wmu[k * 32 + t], mu);
      lv = fmaf(gm[k], Wlv[k * 32 + t], lv);
    }
    zs[t] = mu + eps[t] * expf(0.5f * lv);
    out[16 + 4 * (size_t)E + t] = mu;          // mu
    out[16 + 4 * (size_t)E + 32 + t] = lv;     // logvar
  }
  __syncthreads();
  if (t < 16) {
    float v = bn[t];
#pragma unroll
    for (int j = 0; j < 32; ++j) v = fmaf(zs[j], Wn[j * 16 + t], v);
    out[t] = v;                                 // node_logits
  }
  {
    float v = be1[t];
#pragma unroll 8
    for (int j = 0; j < 32; ++j)
      v = fmaf(zs[j], We1[j * 128 + t] + We1[(j + 32) * 128 + t], v);
    eh[t] = fmaxf(v, 0.f);
  }
  __syncthreads();
  if (t < 4) {
    float v = be2[t];
#pragma unroll 8
    for (int k = 0; k < 128; ++k) v = fmaf(eh[k], We2[k * 4 + t], v);
    el4[t] = v;
  }
}

// ---------------- broadcast edge_logits ----------------
__global__ __launch_bounds__(256) void bcast_edges(const float* __restrict__ el4,
                                                   float* __restrict__ out16, int E) {
  int i = blockIdx.x * 256 + threadIdx.x;
  if (i < E) {
    float4 v = *(const float4*)el4;
    ((float4*)out16)[i] = v;
  }
}

extern "C" void kernel_launch(void* const* d_in, const int* in_sizes, int n_in,
                              void* d_out, int out_size, void* d_ws, size_t ws_size,
                              hipStream_t stream) {
  const float* x   = (const float*)d_in[0];
  const int*   ei  = (const int*)d_in[1];
  const float* eps = (const float*)d_in[2];
  const float* W1  = (const float*)d_in[3];
  const float* b1  = (const float*)d_in[4];
  const float* W2  = (const float*)d_in[5];
  const float* b2  = (const float*)d_in[6];
  const float* Wmu = (const float*)d_in[7];
  const float* bmu = (const float*)d_in[8];
  const float* Wlv = (const float*)d_in[9];
  const float* blv = (const float*)d_in[10];
  const float* Wn  = (const float*)d_in[11];
  const float* bn  = (const float*)d_in[12];
  const float* We1 = (const float*)d_in[13];
  const float* be1 = (const float*)d_in[14];
  const float* We2 = (const float*)d_in[15];
  const float* be2 = (const float*)d_in[16];

  const int N = in_sizes[0] / FDIM;
  const int E = in_sizes[1] / 2;
  const int* row = ei;
  const int* col = ei + E;
  float* out = (float*)d_out;

  const int nscan = (N + SCAN_B - 1) / SCAN_B;
  const int ntiles = (N + 63) / 64;

  char* ws = (char*)d_ws;
  size_t off = 0;
  float* deg    = (float*)(ws + off); off += (size_t)N * 4;
  float* dis    = (float*)(ws + off); off += (size_t)N * 4;
  float* nrm    = (float*)(ws + off); off += (size_t)E * 4;
  int*   rs     = (int*)(ws + off);   off += ((size_t)N + 1) * 4;
  int*   cursor = (int*)(ws + off);   off += (size_t)N * 4;
  int*   part   = (int*)(ws + off);   off += (size_t)nscan * 4;
  int*   csrcol = (int*)(ws + off);   off += (size_t)E * 4;
  float* g      = (float*)(ws + off); off += 128 * 4;
  float* el4    = (float*)(ws + off); off += 4 * 4;
  off = (off + 1023) & ~(size_t)1023;
  unsigned short* Wimg1 = (unsigned short*)(ws + off); off += 16384 * 2;
  unsigned short* Wimg2 = (unsigned short*)(ws + off); off += 16384 * 2;
  off = (off + 1023) & ~(size_t)1023;
  unsigned short* scaled = (unsigned short*)(ws + off); off += (size_t)N * FDIM * 2;
  off = (off + 1023) & ~(size_t)1023;
  unsigned short* h1     = (unsigned short*)(ws + off); off += (size_t)N * FDIM * 2;
  off += 16384;  // pad: gemm2 may stage one partial tile past h1 end

  hipMemsetAsync(deg, 0, (size_t)N * 4, stream);
  hipMemsetAsync(g, 0, 128 * 4, stream);

  // W images + degree + CSR(+norm)
  prep_w<<<64, 256, 0, stream>>>(W1, W2, Wimg1, Wimg2);
  count_deg<<<(E + 255) / 256, 256, 0, stream>>>(row, deg, E);
  scan1<<<nscan, SCAN_B, 0, stream>>>(deg, dis, rs, part, N);
  scan2<<<1, SCAN_B, 0, stream>>>(part, nscan);
  scan3<<<nscan, SCAN_B, 0, stream>>>(rs, part, cursor, N, E);
  fill_csr_norm<<<(E + 255) / 256, 256, 0, stream>>>(row, col, dis, cursor, csrcol, nrm, E);

  // conv1
  gemm1_scale<<<1280, 256, 0, stream>>>(x, Wimg1, b1, nrm, scaled, N, ntiles);
  aggregate_h<<<((size_t)(N + 3) / 4 * 16 + 255) / 256, 256, 0, stream>>>(scaled, rs, csrcol, h1, N);

  // conv2 (+ fused mean)
  gemm2_scale<<<1280, 256, 0, stream>>>(h1, Wimg2, b2, nrm, scaled, N, ntiles);
  aggregate_mean<<<1024, 256, 0, stream>>>(scaled, rs, csrcol, g, N);

  // tail + broadcast
  tail_kernel<<<1, 128, 0, stream>>>(g, eps, Wmu, bmu, Wlv, blv, Wn, bn,
                                     We1, be1, We2, be2, out, el4, N, E);
  bcast_edges<<<(E + 255) / 256, 256, 0, stream>>>(el4, out + 16, E);
}